// Round 2
// baseline (995.443 us; speedup 1.0000x reference)
//
#include <hip/hip_runtime.h>

#define NG 256
#define PI2F 6.28318530717958647692f

// ---------------------------------------------------------------------------
// 256-point radix-2 Stockham FFT in LDS (OTFFT fft0 formulation).
// a: input buffer (result ends up back in a after 8 stages), b: ping-pong tmp.
// t: butterfly index 0..127. All threads of the block must call (barriers).
// ---------------------------------------------------------------------------
template<bool INV>
__device__ __forceinline__ void fft256_block(float2* a, float2* b, int t, bool active)
{
    int s = 1;
#pragma unroll
    for (int stage = 0; stage < 8; ++stage) {
        __syncthreads();
        if (active) {
            const int p = t >> stage;
            const int q = t & (s - 1);
            const int n = 256 >> stage;
            const float2 x0 = a[q + s * p];
            const float2 x1 = a[q + s * p + 128];       // + s*m, s*m==128 always
            const float ang = (INV ? PI2F : -PI2F) * (float)p / (float)n;
            float sw, cw;
            __sincosf(ang, &sw, &cw);
            const float dx = x0.x - x1.x;
            const float dy = x0.y - x1.y;
            b[q + 2 * s * p]     = make_float2(x0.x + x1.x, x0.y + x1.y);
            b[q + 2 * s * p + s] = make_float2(dx * cw - dy * sw, dx * sw + dy * cw);
        }
        float2* tmp = a; a = b; b = tmp;
        s <<= 1;
    }
    __syncthreads();
}

// ---------------------------------------------------------------------------
// Pass A: forward FFT along x for each row y; write transposed At[b][kx][y].
// ---------------------------------------------------------------------------
__global__ void __launch_bounds__(128)
fftA_kernel(const float* __restrict__ zsrc, float2* __restrict__ At)
{
    __shared__ float2 bufA[256];
    __shared__ float2 bufB[256];
    const int y = blockIdx.x, b = blockIdx.y;
    const int t = threadIdx.x;
    const float* row = zsrc + (b * NG + y) * NG;
    bufA[t]       = make_float2(row[t], 0.f);
    bufA[t + 128] = make_float2(row[t + 128], 0.f);
    fft256_block<false>(bufA, bufB, t, true);
    At[(b * NG + t) * NG + y]       = bufA[t];
    At[(b * NG + t + 128) * NG + y] = bufA[t + 128];
}

// ---------------------------------------------------------------------------
// Pass B+C fused: forward FFT along y (input row At[b][kx][:] is contiguous),
// spectral multiplies, then TWO inverse FFTs along ky (fields packed):
//   field0 = -(kxm + i kym)*inv_lap*zh  -> ifft2 gives u + i v
//   field1 = (-kym + i kxm)*zh          -> ifft2 gives zx + i zy
// kxm/kym are Hermitian-projection-masked wavenumbers: the packing
// a+ib requires ifft(A),ifft(B) exactly real; anti-Hermitian Nyquist
// lines (self-mirrored under k->-k with odd multiplier) must be zeroed —
// this reproduces the reference's Re(ifft(...)) exactly.
// Write transposed Ct[f][b][y][kx], scaled by 1/256 (first half of 1/N^2).
// ---------------------------------------------------------------------------
__global__ void __launch_bounds__(256)
fftBC_kernel(const float2* __restrict__ At,
             float2* __restrict__ Ct0, float2* __restrict__ Ct1)
{
    __shared__ float2 bA[256];
    __shared__ float2 bB[256];
    __shared__ float2 bC[256];
    __shared__ float2 bD[256];
    const int kx = blockIdx.x, b = blockIdx.y;
    const int t = threadIdx.x;
    bA[t] = At[(b * NG + kx) * NG + t];
    fft256_block<false>(bA, bB, t, t < 128);   // zh_t[kx][ky] now in bA

    const float kxv = (kx < 128) ? (float)kx : (float)(kx - 256);
    const float kyv = (t  < 128) ? (float)t  : (float)(t  - 256);
    const float K2  = kxv * kxv + kyv * kyv;
    const float il  = (K2 > 0.f) ? (-1.f / K2) : 0.f;
    // Hermitian-projection masks (zero the anti-Hermitian Nyquist line):
    const float kxm = (kx == 128) ? 0.f : kxv;  // KX-multiplied parts (v, zx)
    const float kym = (t  == 128) ? 0.f : kyv;  // KY-multiplied parts (u, zy)
    const float2 Z  = bA[t];
    // S1 = -(kxm + i kym) * il * Z
    const float ar = -kxm * il, ai = -kym * il;
    const float2 S1 = make_float2(ar * Z.x - ai * Z.y, ar * Z.y + ai * Z.x);
    // S2 = (-kym + i kxm) * Z
    const float2 S2 = make_float2(-kym * Z.x - kxm * Z.y, -kym * Z.y + kxm * Z.x);
    bA[t] = S1;            // per-thread same-slot overwrite: no race
    bC[t] = S2;

    float2* pa = (t < 128) ? bA : bC;
    float2* pb = (t < 128) ? bB : bD;
    fft256_block<true>(pa, pb, t & 127, true); // results in bA (f0), bC (f1)

    const float sc = 1.f / 256.f;
    const float2 r0 = bA[t];
    const float2 r1 = bC[t];
    Ct0[(b * NG + t) * NG + kx] = make_float2(r0.x * sc, r0.y * sc);
    Ct1[(b * NG + t) * NG + kx] = make_float2(r1.x * sc, r1.y * sc);
}

// ---------------------------------------------------------------------------
// Pass D: inverse FFT along kx for both fields (rows Ct[f][b][y][:]
// contiguous), then fused time-step update. Optionally writes output slot.
// ---------------------------------------------------------------------------
__global__ void __launch_bounds__(256)
fftD_kernel(const float2* __restrict__ Ct0, const float2* __restrict__ Ct1,
            const float* __restrict__ zsrc, const float* __restrict__ Qb,
            float* __restrict__ zdst, float* __restrict__ outp)
{
    __shared__ float2 bA[256];
    __shared__ float2 bB[256];
    __shared__ float2 bC[256];
    __shared__ float2 bD[256];
    const int y = blockIdx.x, b = blockIdx.y;
    const int t = threadIdx.x;
    bA[t] = Ct0[(b * NG + y) * NG + t];
    bC[t] = Ct1[(b * NG + y) * NG + t];
    float2* pa = (t < 128) ? bA : bC;
    float2* pb = (t < 128) ? bB : bD;
    fft256_block<true>(pa, pb, t & 127, true);

    const float sc = 1.f / 256.f;      // second half of 1/N^2
    const float u  = bA[t].x * sc, v  = bA[t].y * sc;
    const float zx = bC[t].x * sc, zy = bC[t].y * sc;
    const int idx = (b * NG + y) * NG + t;
    const float z0 = zsrc[idx];
    const float q  = Qb[idx];
    const float adv = u * zx + v * zy;
    const float zn = z0 + 0.01f * (-adv - 0.5f * v - 0.05f * z0 + q);
    zdst[idx] = zn;
    if (outp) outp[b * (4 * NG * NG) + y * NG + t] = zn;
}

// ---------------------------------------------------------------------------
// Fused CNN forcing: Q = Q0 + 0.01 * conv2(relu(conv1(z))), SAME zero padding.
// 16x16 output tile per 256-thread block; h staged in LDS as float4 channel
// groups, cell padded to 36 floats for balanced banks.
// ---------------------------------------------------------------------------
#define HT_CELL 36

__global__ void __launch_bounds__(256)
conv_kernel(const float* __restrict__ zsrc, const float* __restrict__ Q0,
            const float* __restrict__ W1, const float* __restrict__ b1,
            const float* __restrict__ W2, const float* __restrict__ b2,
            float* __restrict__ Qout)
{
    __shared__ float zt[20][20];
    __shared__ __align__(16) float ht[18 * 18 * HT_CELL]; // 46656 B
    __shared__ float4 w1s[72];
    __shared__ float4 w2s[72];
    __shared__ float b1s[32];
    __shared__ float b2s;

    const int b = blockIdx.z;
    const int ty0 = blockIdx.y * 16, tx0 = blockIdx.x * 16;
    const int tid = threadIdx.x;

    if (tid < 72) {
        w1s[tid] = ((const float4*)W1)[tid];
        w2s[tid] = ((const float4*)W2)[tid];
    }
    if (tid < 32) b1s[tid] = b1[tid];
    if (tid == 0) b2s = b2[0];

    for (int i = tid; i < 400; i += 256) {
        const int ly = i / 20, lx = i - ly * 20;
        const int gy = ty0 + ly - 2, gx = tx0 + lx - 2;
        float v = 0.f;
        if ((unsigned)gy < 256u && (unsigned)gx < 256u)
            v = zsrc[(b * NG + gy) * NG + gx];
        zt[ly][lx] = v;
    }
    __syncthreads();

    // conv1 + ReLU over 18x18 halo region, 8 channel-groups of 4
    for (int i = tid; i < 324 * 8; i += 256) {
        const int pos = i >> 3, cg = i & 7;
        const int hy = pos / 18, hx = pos - hy * 18;
        const int gy = ty0 + hy - 1, gx = tx0 + hx - 1;
        float4 acc = make_float4(0.f, 0.f, 0.f, 0.f);
        if ((unsigned)gy < 256u && (unsigned)gx < 256u) {
            acc = make_float4(b1s[cg * 4], b1s[cg * 4 + 1],
                              b1s[cg * 4 + 2], b1s[cg * 4 + 3]);
#pragma unroll
            for (int dy = 0; dy < 3; dy++)
#pragma unroll
                for (int dx = 0; dx < 3; dx++) {
                    const float zv = zt[hy + dy][hx + dx];
                    const float4 w = w1s[(dy * 3 + dx) * 8 + cg];
                    acc.x += w.x * zv; acc.y += w.y * zv;
                    acc.z += w.z * zv; acc.w += w.w * zv;
                }
            acc.x = fmaxf(acc.x, 0.f); acc.y = fmaxf(acc.y, 0.f);
            acc.z = fmaxf(acc.z, 0.f); acc.w = fmaxf(acc.w, 0.f);
        }
        *((float4*)&ht[pos * HT_CELL + cg * 4]) = acc;  // 0 outside image
    }
    __syncthreads();

    // conv2: one output pixel per thread
    const int oy = tid >> 4, ox = tid & 15;
    float q = b2s;
#pragma unroll
    for (int dy = 0; dy < 3; dy++)
#pragma unroll
        for (int dx = 0; dx < 3; dx++) {
            const float* hcell = &ht[((oy + dy) * 18 + (ox + dx)) * HT_CELL];
#pragma unroll
            for (int cg = 0; cg < 8; cg++) {
                const float4 hv = *((const float4*)&hcell[cg * 4]);
                const float4 w  = w2s[(dy * 3 + dx) * 8 + cg];
                q += w.x * hv.x + w.y * hv.y + w.z * hv.z + w.w * hv.w;
            }
        }
    const int gy = ty0 + oy, gx = tx0 + ox;
    const int idx = (b * NG + gy) * NG + gx;
    Qout[idx] = Q0[gy * NG + gx] + 0.01f * q;
}

// ---------------------------------------------------------------------------
extern "C" void kernel_launch(void* const* d_in, const int* in_sizes, int n_in,
                              void* d_out, int out_size, void* d_ws, size_t ws_size,
                              hipStream_t stream)
{
    const float* zeta = (const float*)d_in[0];   // (8,256,256)
    const float* Q0   = (const float*)d_in[1];   // (256,256)
    const float* W1   = (const float*)d_in[2];   // (3,3,1,32)
    const float* b1   = (const float*)d_in[3];   // (32,)
    const float* W2   = (const float*)d_in[4];   // (3,3,32,1)
    const float* b2   = (const float*)d_in[5];   // (1,)
    float* outp = (float*)d_out;                 // (8,4,256,256)

    char* ws = (char*)d_ws;
    float*  zbuf = (float*)(ws);                       // 2 MB
    float*  Qb   = (float*)(ws + (2u << 20));          // 2 MB
    float2* At   = (float2*)(ws + (4u << 20));         // 4 MB
    float2* Ct0  = (float2*)(ws + (8u << 20));         // 4 MB
    float2* Ct1  = (float2*)(ws + (12u << 20));        // 4 MB
    if (ws_size < (16u << 20)) return;                 // need 16 MB scratch

    const dim3 gConv(16, 16, 8);
    const dim3 gFft(NG, 8);

    for (int step = 0; step < 16; ++step) {
        const float* zs = (step == 0) ? zeta : zbuf;
        conv_kernel<<<gConv, 256, 0, stream>>>(zs, Q0, W1, b1, W2, b2, Qb);
        fftA_kernel<<<gFft, 128, 0, stream>>>(zs, At);
        fftBC_kernel<<<gFft, 256, 0, stream>>>(At, Ct0, Ct1);
        float* op = ((step & 3) == 3) ? (outp + (size_t)(step >> 2) * NG * NG)
                                      : nullptr;
        fftD_kernel<<<gFft, 256, 0, stream>>>(Ct0, Ct1, zs, Qb, zbuf, op);
    }
}

// Round 3
// 721.676 us; speedup vs baseline: 1.3793x; 1.3793x over previous
//
#include <hip/hip_runtime.h>

#define NG 256
#define PI2F 6.28318530717958647692f
// padded LDS complex index: pad 1 float2 per 16 to break bank aliasing
#define PIDX(i) ((i) + ((i) >> 4))

__device__ __forceinline__ float2 f2add(float2 a, float2 b){ return make_float2(a.x+b.x, a.y+b.y); }
__device__ __forceinline__ float2 f2sub(float2 a, float2 b){ return make_float2(a.x-b.x, a.y-b.y); }
__device__ __forceinline__ float2 cmul(float2 a, float2 b){ return make_float2(a.x*b.x - a.y*b.y, a.x*b.y + a.y*b.x); }

// ---------------------------------------------------------------------------
// 256-pt radix-4 Stockham FFT, 64 threads per FFT unit (u = lane 0..63).
// Buffers a,b are PIDX-padded (272 float2). Twiddle table tw[j]=exp(-2πi j/256).
// Result ends back in `a`. Caller must __syncthreads() after filling a/tw.
// Derivation (DIF): X[4u+c] = DFT_m{ W^(p c) * B_c[p] },
//   B0=a+b+c+d, B1=(a-c)-j(b-d), B2=(a+c)-(b+d), B3=(a-c)+j(b-d)  (fwd)
// Verified against the DFT definition at N=4.
// ---------------------------------------------------------------------------
template<bool INV>
__device__ __forceinline__ void fft256_r4(float2* a, float2* b, const float2* tw, int u)
{
#pragma unroll
    for (int st = 0; st < 4; ++st) {
        const int sl = 2 * st;
        const int q  = u & ((1 << sl) - 1);
        const int j1 = u - q;                 // p << sl  (twiddle index, <64)
        const float2 x0 = a[PIDX(u)];
        const float2 x1 = a[PIDX(u + 64)];
        const float2 x2 = a[PIDX(u + 128)];
        const float2 x3 = a[PIDX(u + 192)];
        float2 w1 = tw[j1];
        if (INV) w1.y = -w1.y;
        const float2 w2 = cmul(w1, w1);
        const float2 w3 = cmul(w1, w2);
        const float2 apc = f2add(x0, x2), amc = f2sub(x0, x2);
        const float2 bpd = f2add(x1, x3), bmd = f2sub(x1, x3);
        const float2 jb  = make_float2(-bmd.y, bmd.x);      // j*(b-d)
        const float2 t0  = f2add(apc, bpd);
        const float2 t2  = f2sub(apc, bpd);
        const float2 t1  = INV ? f2add(amc, jb) : f2sub(amc, jb);
        const float2 t3  = INV ? f2sub(amc, jb) : f2add(amc, jb);
        const int wb = q + (j1 << 2);         // q + 4*s*p
        const int ss = 1 << sl;
        b[PIDX(wb)]          = t0;
        b[PIDX(wb + ss)]     = cmul(w1, t1);
        b[PIDX(wb + 2 * ss)] = cmul(w2, t2);
        b[PIDX(wb + 3 * ss)] = cmul(w3, t3);
        __syncthreads();
        float2* tmp = a; a = b; b = tmp;
    }
}

__device__ __forceinline__ void init_tw(float2* tw, int tid)
{
    float s, c;
    __sincosf(-PI2F * (float)tid * (1.f / 256.f), &s, &c);
    tw[tid] = make_float2(c, s);
}

// ---------------------------------------------------------------------------
// STEP1: fused  [conv blocks: 0..2047]  +  [fftA blocks: 2048..2303]
// conv: Q = Q0 + 0.01*conv2(relu(conv1(z))), 16x16 tile per block (validated).
// fftA: 8 rows per block as 4 row-packed complex FFTs (r0 + i*r1), Hermitian
//       unpack, coalesced transposed write At[b][kx][y] (64B per lane).
// ---------------------------------------------------------------------------
#define HT_CELL 36
#define S1_POOL 50704

__global__ void __launch_bounds__(256)
step1_kernel(const float* __restrict__ zsrc, const float* __restrict__ Q0,
             const float* __restrict__ W1, const float* __restrict__ b1,
             const float* __restrict__ W2, const float* __restrict__ b2,
             float* __restrict__ Qout, float2* __restrict__ At)
{
    __shared__ __align__(16) char pool[S1_POOL];
    const int bid = blockIdx.x;
    const int tid = threadIdx.x;

    if (bid < 2048) {
        // ---------------- conv role ----------------
        float*  zt  = (float*)pool;                       // 20*20*4 = 1600
        float*  ht  = (float*)(pool + 1600);              // 18*18*36*4 = 46656
        float4* w1s = (float4*)(pool + 48256);            // 1152
        float4* w2s = (float4*)(pool + 49408);            // 1152
        float*  b1s = (float*)(pool + 50560);             // 128
        float*  b2s = (float*)(pool + 50688);             // 4

        const int b   = bid >> 8;
        const int ty0 = ((bid >> 4) & 15) * 16, tx0 = (bid & 15) * 16;

        if (tid < 72) {
            w1s[tid] = ((const float4*)W1)[tid];
            w2s[tid] = ((const float4*)W2)[tid];
        }
        if (tid < 32) b1s[tid] = b1[tid];
        if (tid == 0) b2s[0] = b2[0];

        for (int i = tid; i < 400; i += 256) {
            const int ly = i / 20, lx = i - ly * 20;
            const int gy = ty0 + ly - 2, gx = tx0 + lx - 2;
            float v = 0.f;
            if ((unsigned)gy < 256u && (unsigned)gx < 256u)
                v = zsrc[(b * NG + gy) * NG + gx];
            zt[ly * 20 + lx] = v;
        }
        __syncthreads();

        for (int i = tid; i < 324 * 8; i += 256) {
            const int pos = i >> 3, cg = i & 7;
            const int hy = pos / 18, hx = pos - hy * 18;
            const int gy = ty0 + hy - 1, gx = tx0 + hx - 1;
            float4 acc = make_float4(0.f, 0.f, 0.f, 0.f);
            if ((unsigned)gy < 256u && (unsigned)gx < 256u) {
                acc = make_float4(b1s[cg * 4], b1s[cg * 4 + 1],
                                  b1s[cg * 4 + 2], b1s[cg * 4 + 3]);
#pragma unroll
                for (int dy = 0; dy < 3; dy++)
#pragma unroll
                    for (int dx = 0; dx < 3; dx++) {
                        const float zv = zt[(hy + dy) * 20 + hx + dx];
                        const float4 w = w1s[(dy * 3 + dx) * 8 + cg];
                        acc.x += w.x * zv; acc.y += w.y * zv;
                        acc.z += w.z * zv; acc.w += w.w * zv;
                    }
                acc.x = fmaxf(acc.x, 0.f); acc.y = fmaxf(acc.y, 0.f);
                acc.z = fmaxf(acc.z, 0.f); acc.w = fmaxf(acc.w, 0.f);
            }
            *((float4*)&ht[pos * HT_CELL + cg * 4]) = acc;
        }
        __syncthreads();

        const int oy = tid >> 4, ox = tid & 15;
        float qv = b2s[0];
#pragma unroll
        for (int dy = 0; dy < 3; dy++)
#pragma unroll
            for (int dx = 0; dx < 3; dx++) {
                const float* hcell = &ht[((oy + dy) * 18 + (ox + dx)) * HT_CELL];
#pragma unroll
                for (int cg = 0; cg < 8; cg++) {
                    const float4 hv = *((const float4*)&hcell[cg * 4]);
                    const float4 w  = w2s[(dy * 3 + dx) * 8 + cg];
                    qv += w.x * hv.x + w.y * hv.y + w.z * hv.z + w.w * hv.w;
                }
            }
        const int gy = ty0 + oy, gx = tx0 + ox;
        Qout[(b * NG + gy) * NG + gx] = Q0[gy * NG + gx] + 0.01f * qv;
    } else {
        // ---------------- fftA role ----------------
        float2* bufs = (float2*)pool;          // A_j = j*272, B_j = (4+j)*272
        float2* tw   = bufs + 2176;
        const int g  = bid - 2048;             // 0..255
        const int b  = g >> 5;
        const int rg = g & 31;                 // row group of 8
        const int j  = tid >> 6, u = tid & 63;
        float2* A = bufs + j * 272;
        float2* B = bufs + (4 + j) * 272;

        init_tw(tw, tid);
        const int ya = rg * 8 + 2 * j;
        const float* r0 = zsrc + (b * NG + ya) * NG;
        const float* r1 = r0 + NG;
#pragma unroll
        for (int r = 0; r < 4; ++r) {
            const int x = u + 64 * r;
            A[PIDX(x)] = make_float2(r0[x], r1[x]);
        }
        __syncthreads();
        fft256_r4<false>(A, B, tw, u);

        // Hermitian unpack (rows ya: Z1, ya+1: Z2) + coalesced write
        const int k  = tid;
        const int km = (256 - k) & 255;
        float2 outv[8];
#pragma unroll
        for (int jj = 0; jj < 4; ++jj) {
            const float2* Aj = bufs + jj * 272;
            const float2 Zk = Aj[PIDX(k)], Zm = Aj[PIDX(km)];
            outv[2 * jj] = make_float2(0.5f * (Zk.x + Zm.x), 0.5f * (Zk.y - Zm.y));
            const float dx = Zk.x - Zm.x, dy = Zk.y + Zm.y;
            outv[2 * jj + 1] = make_float2(0.5f * dy, -0.5f * dx);
        }
        float4* dst = (float4*)(At + ((size_t)(b * NG + k)) * NG + rg * 8);
#pragma unroll
        for (int q4 = 0; q4 < 4; ++q4) dst[q4] = ((float4*)outv)[q4];
    }
}

// ---------------------------------------------------------------------------
// BC: 4 kx-lines per block. fwd FFT along y, spectral multiplies (with the
// Hermitian-projection Nyquist masks — see round-2 derivation), two packed
// inverse FFTs, coalesced transposed writes Ct[f][b][y][kx] (x 1/256).
// ---------------------------------------------------------------------------
#define BC_POOL 28160

__global__ void __launch_bounds__(256)
fftBC_kernel(const float2* __restrict__ At,
             float2* __restrict__ Ct0, float2* __restrict__ Ct1)
{
    __shared__ __align__(16) char pool[BC_POOL];
    float2* bufs = (float2*)pool;   // A_j = j*272, B_j = (4+j)*272, C_j = (8+j)*272
    float2* tw   = bufs + 3264;
    const int bid = blockIdx.x;
    const int b  = bid >> 6;
    const int kg = bid & 63;
    const int tid = threadIdx.x;
    const int j = tid >> 6, u = tid & 63;
    float2* A = bufs + j * 272;
    float2* B = bufs + (4 + j) * 272;
    float2* C = bufs + (8 + j) * 272;

    init_tw(tw, tid);
    const int kxl = 4 * kg + j;
    const float2* src = At + ((size_t)(b * NG + kxl)) * NG;
#pragma unroll
    for (int r = 0; r < 4; ++r) {
        const int x = u + 64 * r;
        A[PIDX(x)] = src[x];
    }
    __syncthreads();
    fft256_r4<false>(A, B, tw, u);

    const float kxv = (kxl < 128) ? (float)kxl : (float)(kxl - 256);
    const float kxm = (kxl == 128) ? 0.f : kxv;
#pragma unroll
    for (int r = 0; r < 4; ++r) {
        const int ky = u + 64 * r;
        const float kyv = (ky < 128) ? (float)ky : (float)(ky - 256);
        const float kym = (ky == 128) ? 0.f : kyv;
        const float K2 = kxv * kxv + kyv * kyv;
        const float il = (K2 > 0.f) ? (-1.f / K2) : 0.f;
        const float2 Z = A[PIDX(ky)];
        const float ar = -kxm * il, ai = -kym * il;
        A[PIDX(ky)] = make_float2(ar * Z.x - ai * Z.y, ar * Z.y + ai * Z.x);
        C[PIDX(ky)] = make_float2(-kym * Z.x - kxm * Z.y, -kym * Z.y + kxm * Z.x);
    }
    __syncthreads();

    fft256_r4<true>(A, B, tw, u);
    {   // coalesced write of field0 (u + i v), thread tid = y
        const int y = tid;
        const float sc = 1.f / 256.f;
        float2 ov[4];
#pragma unroll
        for (int jj = 0; jj < 4; ++jj) {
            const float2 r0 = (bufs + jj * 272)[PIDX(y)];
            ov[jj] = make_float2(r0.x * sc, r0.y * sc);
        }
        float4* dst = (float4*)(Ct0 + ((size_t)(b * NG + y)) * NG + 4 * kg);
        dst[0] = ((float4*)ov)[0];
        dst[1] = ((float4*)ov)[1];
    }
    fft256_r4<true>(C, B, tw, u);
    {   // coalesced write of field1 (zx + i zy)
        const int y = tid;
        const float sc = 1.f / 256.f;
        float2 ov[4];
#pragma unroll
        for (int jj = 0; jj < 4; ++jj) {
            const float2 r1 = (bufs + (8 + jj) * 272)[PIDX(y)];
            ov[jj] = make_float2(r1.x * sc, r1.y * sc);
        }
        float4* dst = (float4*)(Ct1 + ((size_t)(b * NG + y)) * NG + 4 * kg);
        dst[0] = ((float4*)ov)[0];
        dst[1] = ((float4*)ov)[1];
    }
}

// ---------------------------------------------------------------------------
// D: 2 (y,b)-lines per block, 4 inverse FFTs (units: y0/f0, y0/f1, y1/f0,
// y1/f1), then the fused time-step update (+ optional output slot).
// ---------------------------------------------------------------------------
#define D_POOL 19456

__global__ void __launch_bounds__(256)
fftD_kernel(const float2* __restrict__ Ct0, const float2* __restrict__ Ct1,
            const float* __restrict__ zsrc, const float* __restrict__ Qb,
            float* __restrict__ zdst, float* __restrict__ outp)
{
    __shared__ __align__(16) char pool[D_POOL];
    float2* bufs = (float2*)pool;   // A_j = j*272, B_j = (4+j)*272
    float2* tw   = bufs + 2176;
    const int bid = blockIdx.x;
    const int b  = bid >> 7;
    const int yg = bid & 127;
    const int y0 = 2 * yg;
    const int tid = threadIdx.x;
    const int j = tid >> 6, u = tid & 63;
    float2* A = bufs + j * 272;
    float2* B = bufs + (4 + j) * 272;

    init_tw(tw, tid);
    const int   yl  = y0 + (j >> 1);
    const float2* src = ((j & 1) ? Ct1 : Ct0) + ((size_t)(b * NG + yl)) * NG;
#pragma unroll
    for (int r = 0; r < 4; ++r) {
        const int x = u + 64 * r;
        A[PIDX(x)] = src[x];
    }
    __syncthreads();
    fft256_r4<true>(A, B, tw, u);

    const float sc = 1.f / 256.f;
#pragma unroll
    for (int i0 = 0; i0 < 2; ++i0) {
        const int i  = tid + 256 * i0;
        const int ln = i >> 8, x = i & 255;
        const float2 uvv = (bufs + (2 * ln) * 272)[PIDX(x)];
        const float2 gzz = (bufs + (2 * ln + 1) * 272)[PIDX(x)];
        const float uu = uvv.x * sc, vv = uvv.y * sc;
        const float zx = gzz.x * sc, zy = gzz.y * sc;
        const int idx = (b * NG + y0 + ln) * NG + x;
        const float z0 = zsrc[idx];
        const float qv = Qb[idx];
        const float adv = uu * zx + vv * zy;
        const float zn = z0 + 0.01f * (-adv - 0.5f * vv - 0.05f * z0 + qv);
        zdst[idx] = zn;
        if (outp) outp[b * (4 * NG * NG) + (y0 + ln) * NG + x] = zn;
    }
}

// ---------------------------------------------------------------------------
extern "C" void kernel_launch(void* const* d_in, const int* in_sizes, int n_in,
                              void* d_out, int out_size, void* d_ws, size_t ws_size,
                              hipStream_t stream)
{
    const float* zeta = (const float*)d_in[0];   // (8,256,256)
    const float* Q0   = (const float*)d_in[1];   // (256,256)
    const float* W1   = (const float*)d_in[2];   // (3,3,1,32)
    const float* b1   = (const float*)d_in[3];   // (32,)
    const float* W2   = (const float*)d_in[4];   // (3,3,32,1)
    const float* b2   = (const float*)d_in[5];   // (1,)
    float* outp = (float*)d_out;                 // (8,4,256,256)

    char* ws = (char*)d_ws;
    float*  zbuf = (float*)(ws);                       // 2 MB
    float*  Qb   = (float*)(ws + (2u << 20));          // 2 MB
    float2* At   = (float2*)(ws + (4u << 20));         // 4 MB
    float2* Ct0  = (float2*)(ws + (8u << 20));         // 4 MB
    float2* Ct1  = (float2*)(ws + (12u << 20));        // 4 MB
    if (ws_size < (16u << 20)) return;                 // need 16 MB scratch

    for (int step = 0; step < 16; ++step) {
        const float* zs = (step == 0) ? zeta : zbuf;
        step1_kernel<<<2304, 256, 0, stream>>>(zs, Q0, W1, b1, W2, b2, Qb, At);
        fftBC_kernel<<<512, 256, 0, stream>>>(At, Ct0, Ct1);
        float* op = ((step & 3) == 3) ? (outp + (size_t)(step >> 2) * NG * NG)
                                      : nullptr;
        fftD_kernel<<<1024, 256, 0, stream>>>(Ct0, Ct1, zs, Qb, zbuf, op);
    }
}